// Round 4
// baseline (2719.870 us; speedup 1.0000x reference)
//
#include <hip/hip_runtime.h>
#include <stdint.h>

typedef __attribute__((ext_vector_type(8))) short s16x8;
typedef __attribute__((ext_vector_type(4))) float f32x4;

static __device__ __forceinline__ unsigned short f2bf(float f) {
  unsigned u = __float_as_uint(f);
  u += 0x7FFFu + ((u >> 16) & 1u);
  return (unsigned short)(u >> 16);
}
static __device__ __forceinline__ float bf2f(unsigned short h) {
  return __uint_as_float(((unsigned)h) << 16);
}

// ---------------- weight prep ----------------
// in [L][K][N] f32 -> out [L][N][K] bf16 (out pre-offset; outL = per-layer out stride in elems)
__global__ void k_wt(const float* __restrict__ in, unsigned short* __restrict__ out,
                     int K, int N, int outL, int total) {
  int idx = blockIdx.x * 256 + threadIdx.x;
  if (idx >= total) return;
  int kn = K * N;
  int l = idx / kn, r = idx - l * kn;
  int k = r / N, n = r - k * N;
  out[(size_t)l * outL + (size_t)n * K + k] = f2bf(in[idx]);
}

// deconv_w [oc][ic][2][2][2] f32 -> Wt_dc[(tap*256+oc)][ic] bf16
__global__ void k_wdc(const float* __restrict__ in, unsigned short* __restrict__ out) {
  int idx = blockIdx.x * 256 + threadIdx.x;      // 524288
  int n = idx >> 8, k = idx & 255;
  out[idx] = f2bf(in[((size_t)(n & 255)) * 2048 + k * 8 + (n >> 8)]);
}

// conv3_w [oc][ic][27] f32 -> wc3[tap][oc][ic] bf16
__global__ void k_wc3(const float* __restrict__ W, unsigned short* __restrict__ T) {
  int idx = blockIdx.x * 256 + threadIdx.x;      // 1327104 = 27*192*256
  int tap = idx / 49152;
  int rem = idx - tap * 49152;
  int oc = rem >> 8, ic = rem & 255;
  T[idx] = f2bf(W[(oc * 256 + ic) * 27 + tap]);
}

__global__ void k_cvt(const float* __restrict__ in, unsigned short* __restrict__ out, int n) {
  int i = blockIdx.x * 256 + threadIdx.x;
  if (i < n) out[i] = f2bf(in[i]);
}

// W_tc [256][768] f32 -> [768][256] f32 (for k_vf)
__global__ void k_wtct(const float* __restrict__ W, float* __restrict__ T) {
  int idx = blockIdx.x * 256 + threadIdx.x;      // 196608
  int k = idx >> 8, o = idx & 255;
  T[idx] = W[o * 768 + k];
}

// ---------------- restore + cam_x (output 2) ----------------
__global__ void k_restore(const float* __restrict__ cx, const int* __restrict__ ids,
                          const float* __restrict__ mtok, float* __restrict__ out) {
  int idx = blockIdx.x * 256 + threadIdx.x;      // 811008 = 6*768*176
  int p = idx % 176;
  int r = idx / 176;
  int ch = r % 768;
  int c = r / 768;
  int id = ids[c * 176 + p];
  out[idx] = (id < 44) ? cx[((size_t)(c * 44 + id)) * 768 + ch] : mtok[ch];
}

// ---------------- vf / feat: relu(camx @ W_tc^T + b) + embeds -> bf16 ----------------
__global__ __launch_bounds__(256) void k_vf(const float* __restrict__ camx, const float* __restrict__ WtT,
                                            const float* __restrict__ btc, const float* __restrict__ cemb,
                                            const float* __restrict__ lemb, unsigned short* __restrict__ featb) {
  __shared__ float sa[768];
  int blk = blockIdx.x;                          // c*176 + p
  int c = blk / 176, p = blk - c * 176;
  int t = threadIdx.x;
  for (int i = t; i < 768; i += 256) sa[i] = camx[((size_t)(c * 768 + i)) * 176 + p];
  __syncthreads();
  float acc = 0.f;
  for (int k = 0; k < 768; ++k) acc += sa[k] * WtT[k * 256 + t];
  featb[(size_t)blk * 256 + t] = f2bf(fmaxf(acc + btc[t], 0.f) + cemb[c * 256 + t] + lemb[t]);
}

// ---------------- bf16 MFMA GEMM, A bf16 [M][lda], B pre-transposed [N][K] bf16 ----------------
// mode 0: f32 out Cf; mode 2: bf16 out Cb (relu applies); mode 1: deconv scatter into Cb
__global__ __launch_bounds__(256) void k_gemm(
    const unsigned short* __restrict__ A, int M, int lda,
    const unsigned short* __restrict__ Bt, int K, int N,
    const float* __restrict__ bias, int relu,
    float* __restrict__ Cf, unsigned short* __restrict__ Cb, int ldc, int mode) {
  __shared__ short sA[128 * 40];
  const int t = threadIdx.x;
  const int l = t & 63, w = t >> 6;
  const int lo = l & 15, kg = l >> 4;
  const int row0 = blockIdx.x * 128, n0 = blockIdx.y * 64;
  const s16x8 bz = {0, 0, 0, 0, 0, 0, 0, 0};
  f32x4 acc[2][4] = {};
  s16x8 bc[4], bn[4];
#pragma unroll
  for (int nb = 0; nb < 4; ++nb) {
    int n = n0 + nb * 16 + lo;
    bc[nb] = (n < N) ? *(const s16x8*)&Bt[(size_t)n * K + kg * 8] : bz;
  }
  const int stR = t >> 1, stH = t & 1;
  for (int kc = 0; kc < K; kc += 32) {
    const bool pf = (kc + 32 < K);
    if (pf) {
#pragma unroll
      for (int nb = 0; nb < 4; ++nb) {
        int n = n0 + nb * 16 + lo;
        bn[nb] = (n < N) ? *(const s16x8*)&Bt[(size_t)n * K + kc + 32 + kg * 8] : bz;
      }
    }
    __syncthreads();
    {
      int r = row0 + stR;
      uint4 v0 = {0u, 0u, 0u, 0u}, v1 = {0u, 0u, 0u, 0u};
      if (r < M) {
        const unsigned short* src = A + (size_t)r * lda + kc + stH * 16;
        v0 = *(const uint4*)src;
        v1 = *(const uint4*)(src + 8);
      }
      *(uint4*)&sA[stR * 40 + stH * 16] = v0;
      *(uint4*)&sA[stR * 40 + stH * 16 + 8] = v1;
    }
    __syncthreads();
    s16x8 a0 = *(const s16x8*)&sA[(w * 32 + lo) * 40 + kg * 8];
    s16x8 a1 = *(const s16x8*)&sA[(w * 32 + 16 + lo) * 40 + kg * 8];
#pragma unroll
    for (int nb = 0; nb < 4; ++nb) {
      acc[0][nb] = __builtin_amdgcn_mfma_f32_16x16x32_bf16(a0, bc[nb], acc[0][nb], 0, 0, 0);
      acc[1][nb] = __builtin_amdgcn_mfma_f32_16x16x32_bf16(a1, bc[nb], acc[1][nb], 0, 0, 0);
    }
    if (pf) {
#pragma unroll
      for (int nb = 0; nb < 4; ++nb) bc[nb] = bn[nb];
    }
  }
#pragma unroll
  for (int m = 0; m < 2; ++m)
#pragma unroll
    for (int nb = 0; nb < 4; ++nb)
#pragma unroll
      for (int r = 0; r < 4; ++r) {
        int row = row0 + w * 32 + m * 16 + (kg << 2) + r;
        int col = n0 + nb * 16 + lo;
        if (row < M && col < N) {
          float v = acc[m][nb][r];
          if (bias) v += bias[col];
          if (relu) v = fmaxf(v, 0.f);
          if (mode == 0) {
            Cf[(size_t)row * ldc + col] = v;
          } else if (mode == 2) {
            Cb[(size_t)row * ldc + col] = f2bf(v);
          } else {
            int tap = col >> 8, oc = col & 255;
            int z = row / 2500, rr = row - z * 2500;
            int hy = rr / 50, wx = rr - hy * 50;
            int t1 = tap >> 2, t2 = (tap >> 1) & 1, t3 = tap & 1;
            int od = 2 * wx + 1 - t1, oh = 2 * hy + 1 - t2, ow = 2 * z + 1 - t3;
            Cb[((size_t)((od * 100 + oh) * 16 + ow)) * 256 + oc] = f2bf(v);
          }
        }
      }
}

// ---------------- split bias for fused off+att projection ----------------
__global__ void k_biasfix(float* __restrict__ oa, const float* __restrict__ boff,
                          const float* __restrict__ batt) {
  int idx = blockIdx.x * 256 + threadIdx.x;   // 20000*288
  if (idx >= 20000 * 288) return;
  int col = idx % 288;
  oa[idx] += (col < 192) ? boff[col] : batt[col - 192];
}

// ---------------- softmax + bilinear sampling + aggregate (-> bf16 agg) ----------------
__global__ __launch_bounds__(256) void k_sample(const float* __restrict__ oa,
                                                const float* __restrict__ val,
                                                unsigned short* __restrict__ aggb) {
  __shared__ float sl[96], sw[96];
  int n = blockIdx.x, t = threadIdx.x;
  if (t < 96) sl[t] = oa[(size_t)n * 288 + 192 + t];
  __syncthreads();
  if (t < 8) {
    float mx = -1e30f;
    for (int j = 0; j < 12; ++j) mx = fmaxf(mx, sl[t * 12 + j]);
    float s = 0.f;
    for (int j = 0; j < 12; ++j) s += __expf(sl[t * 12 + j] - mx);
    float inv = 1.f / s;
    for (int j = 0; j < 12; ++j) sw[t * 12 + j] = __expf(sl[t * 12 + j] - mx) * inv;
  }
  __syncthreads();
  int h = t >> 5, d = t & 31;
  float xr = ((float)(n % 50) + 0.5f) * (22.0f / 50.0f) - 0.5f;
  float yr = ((float)((n / 50) % 50) + 0.5f) * (8.0f / 50.0f) - 0.5f;
  float acc = 0.f;
  const float* offn = oa + (size_t)n * 288 + h * 24;  // [h][c][p][2]
  const float* vbh = val + (size_t)h * 32 + d;
#pragma unroll
  for (int c = 0; c < 6; ++c)
#pragma unroll
    for (int p2 = 0; p2 < 2; ++p2) {
      float x = xr + offn[(c * 2 + p2) * 2];
      float y = yr + offn[(c * 2 + p2) * 2 + 1];
      float x0 = floorf(x), y0 = floorf(y);
      float wx = x - x0, wy = y - y0;
      int ix0 = min(max((int)x0, 0), 21), ix1 = min(max((int)x0 + 1, 0), 21);
      int iy0 = min(max((int)y0, 0), 7), iy1 = min(max((int)y0 + 1, 0), 7);
      const float* vb = vbh + (size_t)c * 176 * 256;
      float v00 = vb[(size_t)(iy0 * 22 + ix0) * 256];
      float v01 = vb[(size_t)(iy0 * 22 + ix1) * 256];
      float v10 = vb[(size_t)(iy1 * 22 + ix0) * 256];
      float v11 = vb[(size_t)(iy1 * 22 + ix1) * 256];
      float bil = (1.f - wx) * (1.f - wy) * v00 + wx * (1.f - wy) * v01 +
                  (1.f - wx) * wy * v10 + wx * wy * v11;
      acc += sw[h * 12 + c * 2 + p2] * bil;
    }
  aggb[(size_t)n * 256 + t] = f2bf(acc);
}

// ---------------- residual + LayerNorm(256): writes q f32 AND qb bf16 ----------------
__global__ __launch_bounds__(256) void k_addln(float* __restrict__ q, const float* __restrict__ p,
                                               const float* __restrict__ g, const float* __restrict__ b,
                                               unsigned short* __restrict__ qb) {
  __shared__ float red[8];
  int n = blockIdx.x, t = threadIdx.x;
  float x = q[(size_t)n * 256 + t] + p[(size_t)n * 256 + t];
  float s1 = x, s2 = x * x;
#pragma unroll
  for (int o = 32; o >= 1; o >>= 1) {
    s1 += __shfl_xor(s1, o, 64);
    s2 += __shfl_xor(s2, o, 64);
  }
  int w = t >> 6;
  if ((t & 63) == 0) { red[w * 2] = s1; red[w * 2 + 1] = s2; }
  __syncthreads();
  s1 = red[0] + red[2] + red[4] + red[6];
  s2 = red[1] + red[3] + red[5] + red[7];
  float mean = s1 * (1.0f / 256.0f);
  float var = s2 * (1.0f / 256.0f) - mean * mean;
  float y = (x - mean) * rsqrtf(var + 1e-5f) * g[t] + b[t];
  q[(size_t)n * 256 + t] = y;
  qb[(size_t)n * 256 + t] = f2bf(y);
}

// ---------------- GroupNorm 1 (256 ch, 16 groups) over x1 [160000][256] bf16 ----------------
__global__ __launch_bounds__(256) void k_gnstat1(const unsigned short* __restrict__ X, float* __restrict__ part) {
  __shared__ float s1[256], s2[256];
  int b = blockIdx.x, t = threadIdx.x;   // 2500 blocks * 16384 elems
  unsigned base = (unsigned)b * 16384u + (unsigned)t;
  float a = 0.f, q = 0.f;
  for (int i = 0; i < 64; ++i) { float v = bf2f(X[base + (unsigned)i * 256u]); a += v; q += v * v; }
  s1[t] = a; s2[t] = q;
  __syncthreads();
  for (int s = 8; s > 0; s >>= 1) {
    if ((t & 15) < s) { s1[t] += s1[t + s]; s2[t] += s2[t + s]; }
    __syncthreads();
  }
  if ((t & 15) == 0) {
    part[(t >> 4) * 2500 + b] = s1[t];
    part[40000 + (t >> 4) * 2500 + b] = s2[t];
  }
}

__global__ __launch_bounds__(256) void k_gnred1(const float* __restrict__ part, float* __restrict__ gmv) {
  __shared__ float s1[256], s2[256];
  int g = blockIdx.x, t = threadIdx.x;   // 16 blocks
  float a = 0.f, q = 0.f;
  for (int i = t; i < 2500; i += 256) { a += part[g * 2500 + i]; q += part[40000 + g * 2500 + i]; }
  s1[t] = a; s2[t] = q;
  __syncthreads();
  for (int s = 128; s > 0; s >>= 1) {
    if (t < s) { s1[t] += s1[t + s]; s2[t] += s2[t + s]; }
    __syncthreads();
  }
  if (t == 0) {
    float m = s1[0] / 2560000.0f;
    float v = s2[0] / 2560000.0f - m * m;
    gmv[2 * g] = m; gmv[2 * g + 1] = rsqrtf(v + 1e-5f);
  }
}

__global__ __launch_bounds__(256) void k_gnapply1(unsigned short* __restrict__ X, const float* __restrict__ gmv,
                                                  const float* __restrict__ g, const float* __restrict__ b) {
  for (unsigned idx = blockIdx.x * 256 + threadIdx.x; idx < 40960000u; idx += gridDim.x * 256) {
    int oc = idx & 255, grp = oc >> 4;
    float v = bf2f(X[idx]);
    v = (v - gmv[grp * 2]) * gmv[grp * 2 + 1] * g[oc] + b[oc];
    X[idx] = f2bf(fmaxf(v, 0.f));
  }
}

// ---------------- conv3 3x3x3 (256->192): A from LDS slab, B global->reg prefetch ----------------
// X: x1 bf16 [vox=100*100*16][256]; Wp: [27][192][256] bf16; Y: [192][160000] bf16
__global__ __launch_bounds__(256, 3) void k_conv3(const unsigned short* __restrict__ X,
                                                  const unsigned short* __restrict__ Wp,
                                                  unsigned short* __restrict__ Y) {
  __shared__ short sX[4 * 543 * 8];    // [kg][pos (543 pad)][8 bf16] = 34.75 KB
  const int od = blockIdx.x;           // 0..99
  const int oh0 = blockIdx.y * 8;      // 0..96
  const int t = threadIdx.x;
  const int l = t & 63, w = t >> 6;
  const int kg = l >> 4, lo = l & 15;
  f32x4 acc[8][3] = {};
  s16x8 bc[3], bn[3];
  const unsigned short* wbase = Wp + (size_t)(w * 48 + lo) * 256 + kg * 8;
#pragma unroll
  for (int nb = 0; nb < 3; ++nb) bc[nb] = *(const s16x8*)&wbase[(size_t)nb * 4096];

  for (int chunk = 0; chunk < 8; ++chunk) {
    __syncthreads();
    // stage slab: 540 pos x 4 kgrp uint4
#pragma unroll
    for (int i = 0; i < 9; ++i) {
      int e = t + i * 256;
      if (e < 2160) {
        int pos = e >> 2, kgs = e & 3;
        int sd = pos / 180, r2 = pos - sd * 180;
        int sh = r2 / 18, sw_ = r2 - sh * 18;
        int gd = od + sd - 1, gh = oh0 + sh - 1, gw = sw_ - 1;
        uint4 v = {0u, 0u, 0u, 0u};
        if ((unsigned)gd < 100u && (unsigned)gh < 100u && (unsigned)gw < 16u)
          v = *(const uint4*)&X[((size_t)((gd * 100 + gh) * 16 + gw)) * 256 + chunk * 32 + kgs * 8];
        *(uint4*)&sX[(kgs * 543 + pos) * 8] = v;
      }
    }
    __syncthreads();
    for (int tap = 0; tap < 27; ++tap) {
      int ntap = tap + 1, nch = chunk;
      if (ntap == 27) { ntap = 0; ++nch; }
      const bool pf = (nch < 8);
      if (pf) {
        const unsigned short* wb = wbase + (size_t)ntap * 49152 + nch * 32;
#pragma unroll
        for (int nb = 0; nb < 3; ++nb) bn[nb] = *(const s16x8*)&wb[(size_t)nb * 4096];
      }
      const int t1 = tap / 9, tr = tap - t1 * 9, t2 = tr / 3, t3 = tr - t2 * 3;
#pragma unroll
      for (int m = 0; m < 8; ++m) {
        int pos = t1 * 180 + (m + t2) * 18 + lo + t3;
        s16x8 a = *(const s16x8*)&sX[(kg * 543 + pos) * 8];
        acc[m][0] = __builtin_amdgcn_mfma_f32_16x16x32_bf16(a, bc[0], acc[m][0], 0, 0, 0);
        acc[m][1] = __builtin_amdgcn_mfma_f32_16x16x32_bf16(a, bc[1], acc[m][1], 0, 0, 0);
        acc[m][2] = __builtin_amdgcn_mfma_f32_16x16x32_bf16(a, bc[2], acc[m][2], 0, 0, 0);
      }
      if (pf) { bc[0] = bn[0]; bc[1] = bn[1]; bc[2] = bn[2]; }
    }
  }
#pragma unroll
  for (int m = 0; m < 8; ++m) {
    int oh = oh0 + m;
    if (oh < 100) {
#pragma unroll
      for (int nb = 0; nb < 3; ++nb)
#pragma unroll
        for (int r = 0; r < 4; ++r) {
          int oc = w * 48 + nb * 16 + lo;
          int ow = (kg << 2) + r;
          Y[(size_t)oc * 160000 + (size_t)((od * 100 + oh) * 16) + ow] = f2bf(acc[m][nb][r]);
        }
    }
  }
}

// ---------------- GroupNorm 2 (192 ch, 16 groups) over [192][160000] bf16 ----------------
__global__ __launch_bounds__(256) void k_gnstat2(const unsigned short* __restrict__ X, float* __restrict__ part) {
  __shared__ float s1[256], s2[256];
  int b = blockIdx.x, t = threadIdx.x;   // 1920 blocks: ch = b/10, part p = b%10
  int ch = b / 10, pp = b - ch * 10;
  unsigned base = (unsigned)ch * 160000u + (unsigned)pp * 16000u;
  float a = 0.f, q = 0.f;
  for (int i = t; i < 16000; i += 256) { float v = bf2f(X[base + i]); a += v; q += v * v; }
  s1[t] = a; s2[t] = q;
  __syncthreads();
  for (int s = 128; s > 0; s >>= 1) {
    if (t < s) { s1[t] += s1[t + s]; s2[t] += s2[t + s]; }
    __syncthreads();
  }
  if (t == 0) { part[80000 + ch * 10 + pp] = s1[0]; part[81920 + ch * 10 + pp] = s2[0]; }
}

__global__ __launch_bounds__(256) void k_gnred2(const float* __restrict__ part, float* __restrict__ gmv) {
  __shared__ float s1[256], s2[256];
  int g = blockIdx.x, t = threadIdx.x;   // 16 blocks, 120 partials each
  float a = (t < 120) ? part[80000 + g * 120 + t] : 0.f;
  float q = (t < 120) ? part[81920 + g * 120 + t] : 0.f;
  s1[t] = a; s2[t] = q;
  __syncthreads();
  for (int s = 128; s > 0; s >>= 1) {
    if (t < s) { s1[t] += s1[t + s]; s2[t] += s2[t + s]; }
    __syncthreads();
  }
  if (t == 0) {
    float m = s1[0] / 1920000.0f;
    float v = s2[0] / 1920000.0f - m * m;
    gmv[2 * g] = m; gmv[2 * g + 1] = rsqrtf(v + 1e-5f);
  }
}

__global__ __launch_bounds__(256) void k_gnapply2(const unsigned short* __restrict__ X, const float* __restrict__ gmv,
                                                  const float* __restrict__ g, const float* __restrict__ b,
                                                  float* __restrict__ out) {
  for (unsigned idx = blockIdx.x * 256 + threadIdx.x; idx < 30720000u; idx += gridDim.x * 256) {
    unsigned oc = idx / 160000u;
    unsigned grp = oc / 12u;
    float v = bf2f(X[idx]);
    v = (v - gmv[grp * 2]) * gmv[grp * 2 + 1] * g[oc] + b[oc];
    out[idx] = fmaxf(v, 0.f);
  }
}

// ---------------- host ----------------
static inline dim3 gemm_grid(int M, int N) { return dim3((M + 127) / 128, (N + 63) / 64); }

extern "C" void kernel_launch(void* const* d_in, const int* in_sizes, int n_in,
                              void* d_out, int out_size, void* d_ws, size_t ws_size,
                              hipStream_t stream) {
  const float* camera_x = (const float*)d_in[0];
  const int* ids = (const int*)d_in[1];
  const float* mask_tok = (const float*)d_in[4];
  const float* vol_emb = (const float*)d_in[5];
  const float* W_tc = (const float*)d_in[6];
  const float* b_tc = (const float*)d_in[7];
  const float* cams_emb = (const float*)d_in[8];
  const float* lvl_emb = (const float*)d_in[9];
  const float* W_off = (const float*)d_in[10];
  const float* b_off = (const float*)d_in[11];
  const float* W_att = (const float*)d_in[12];
  const float* b_att = (const float*)d_in[13];
  const float* W_val = (const float*)d_in[14];
  const float* b_val = (const float*)d_in[15];
  const float* W_out = (const float*)d_in[16];
  const float* b_out = (const float*)d_in[17];
  const float* ln1_g = (const float*)d_in[18];
  const float* ln1_b = (const float*)d_in[19];
  const float* W_ff1 = (const float*)d_in[20];
  const float* b_ff1 = (const float*)d_in[21];
  const float* W_ff2 = (const float*)d_in[22];
  const float* b_ff2 = (const float*)d_in[23];
  const float* ln2_g = (const float*)d_in[24];
  const float* ln2_b = (const float*)d_in[25];
  const float* deconv_w = (const float*)d_in[26];
  const float* gn1_g = (const float*)d_in[27];
  const float* gn1_b = (const float*)d_in[28];
  const float* conv3_w = (const float*)d_in[29];
  const float* gn2_g = (const float*)d_in[30];
  const float* gn2_b = (const float*)d_in[31];

  char* ws = (char*)d_ws;
  float* q             = (float*)(ws + 0);                      // 20.48 MB
  unsigned short* qb   = (unsigned short*)(ws + 20480000);      // 10.24 MB
  float* proj          = (float*)(ws + 30720000);               // 20.48 MB
  float* oa            = (float*)(ws + 51200000);               // 23.04 MB
  unsigned short* aggb = (unsigned short*)(ws + 74240000);      // 10.24 MB
  unsigned short* ffhb = (unsigned short*)(ws + 84480000);      // 20.48 MB
  float* val           = (float*)(ws + 104960000);              // 1.08 MB
  unsigned short* featb= (unsigned short*)(ws + 106041344);     // 0.54 MB
  unsigned short* x1bf = (unsigned short*)(ws + 30720000);      // 81.92 MB (aliases proj..featb; decoder scratch dead)
  unsigned short* c3   = (unsigned short*)(ws + 112640000);     // 61.44 MB
  unsigned short* Wt_val = (unsigned short*)(ws + 174080000);   // 393216 B
  unsigned short* Wt_oa  = (unsigned short*)(ws + 174473216);   // 442368 B
  unsigned short* Wt_out = (unsigned short*)(ws + 174915584);   // 393216 B
  unsigned short* Wt_ff1 = (unsigned short*)(ws + 175308800);   // 786432 B
  unsigned short* Wt_ff2 = (unsigned short*)(ws + 176095232);   // 786432 B
  unsigned short* Wt_dc  = (unsigned short*)(ws + 176881664);   // 1048576 B
  unsigned short* wc3    = (unsigned short*)(ws + 177930240);   // 2654208 B
  float* part = (float*)(ws + 180584448);                       // 336 KB
  float* gmv1 = (float*)(ws + 180920320);
  float* gmv2 = (float*)(ws + 180920448);
  float* wtcT = (float*)(ws + 180920576);                       // 786432 B

  float* out_x = (float*)d_out;
  float* out_camx = out_x + 30720000;

  // weight prep
  k_wtct<<<768, 256, 0, stream>>>(W_tc, wtcT);
  k_wt<<<(3 * 65536 + 255) / 256, 256, 0, stream>>>(W_val, Wt_val, 256, 256, 65536, 3 * 65536);
  k_wt<<<(3 * 49152 + 255) / 256, 256, 0, stream>>>(W_off, Wt_oa, 256, 192, 73728, 3 * 49152);
  k_wt<<<(3 * 24576 + 255) / 256, 256, 0, stream>>>(W_att, Wt_oa + 192 * 256, 256, 96, 73728, 3 * 24576);
  k_wt<<<(3 * 65536 + 255) / 256, 256, 0, stream>>>(W_out, Wt_out, 256, 256, 65536, 3 * 65536);
  k_wt<<<(3 * 131072 + 255) / 256, 256, 0, stream>>>(W_ff1, Wt_ff1, 256, 512, 131072, 3 * 131072);
  k_wt<<<(3 * 131072 + 255) / 256, 256, 0, stream>>>(W_ff2, Wt_ff2, 512, 256, 131072, 3 * 131072);
  k_wdc<<<2048, 256, 0, stream>>>(deconv_w, Wt_dc);
  k_wc3<<<5184, 256, 0, stream>>>(conv3_w, wc3);

  k_restore<<<3168, 256, 0, stream>>>(camera_x, ids, mask_tok, out_camx);
  k_vf<<<1056, 256, 0, stream>>>(out_camx, wtcT, b_tc, cams_emb, lvl_emb, featb);
  hipMemcpyAsync(q, vol_emb, (size_t)20000 * 256 * 4, hipMemcpyDeviceToDevice, stream);
  k_cvt<<<20000, 256, 0, stream>>>(vol_emb, qb, 5120000);

  for (int lyr = 0; lyr < 3; ++lyr) {
    k_gemm<<<gemm_grid(1056, 256), 256, 0, stream>>>(featb, 1056, 256, Wt_val + lyr * 65536, 256, 256,
                                                     b_val + lyr * 256, 0, val, nullptr, 256, 0);
    k_gemm<<<gemm_grid(20000, 288), 256, 0, stream>>>(qb, 20000, 256, Wt_oa + lyr * 73728, 256, 288,
                                                      nullptr, 0, oa, nullptr, 288, 0);
    k_biasfix<<<(20000 * 288 + 255) / 256, 256, 0, stream>>>(oa, b_off + lyr * 192, b_att + lyr * 96);
    k_sample<<<20000, 256, 0, stream>>>(oa, val, aggb);
    k_gemm<<<gemm_grid(20000, 256), 256, 0, stream>>>(aggb, 20000, 256, Wt_out + lyr * 65536, 256, 256,
                                                      b_out + lyr * 256, 0, proj, nullptr, 256, 0);
    k_addln<<<20000, 256, 0, stream>>>(q, proj, ln1_g + lyr * 256, ln1_b + lyr * 256, qb);
    k_gemm<<<gemm_grid(20000, 512), 256, 0, stream>>>(qb, 20000, 256, Wt_ff1 + lyr * 131072, 256, 512,
                                                      b_ff1 + lyr * 512, 1, nullptr, ffhb, 512, 2);
    k_gemm<<<gemm_grid(20000, 256), 256, 0, stream>>>(ffhb, 20000, 512, Wt_ff2 + lyr * 131072, 512, 256,
                                                      b_ff2 + lyr * 256, 0, proj, nullptr, 256, 0);
    k_addln<<<20000, 256, 0, stream>>>(q, proj, ln2_g + lyr * 256, ln2_b + lyr * 256, qb);
  }

  // deconv: all 8 taps in one GEMM (N = 2048), scattered bf16 output
  k_gemm<<<gemm_grid(20000, 2048), 256, 0, stream>>>(qb, 20000, 256, Wt_dc, 256, 2048,
                                                     nullptr, 0, nullptr, x1bf, 256, 1);

  k_gnstat1<<<2500, 256, 0, stream>>>(x1bf, part);
  k_gnred1<<<16, 256, 0, stream>>>(part, gmv1);
  k_gnapply1<<<2048, 256, 0, stream>>>(x1bf, gmv1, gn1_g, gn1_b);

  k_conv3<<<dim3(100, 13), 256, 0, stream>>>(x1bf, wc3, c3);

  k_gnstat2<<<1920, 256, 0, stream>>>(c3, part);
  k_gnred2<<<16, 256, 0, stream>>>(part, gmv2);
  k_gnapply2<<<2048, 256, 0, stream>>>(c3, gmv2, gn2_g, gn2_b, out_x);
}

// Round 5
// 1512.398 us; speedup vs baseline: 1.7984x; 1.7984x over previous
//
#include <hip/hip_runtime.h>
#include <stdint.h>

typedef __attribute__((ext_vector_type(8))) short s16x8;
typedef __attribute__((ext_vector_type(4))) float f32x4;

static __device__ __forceinline__ unsigned short f2bf(float f) {
  unsigned u = __float_as_uint(f);
  u += 0x7FFFu + ((u >> 16) & 1u);
  return (unsigned short)(u >> 16);
}
static __device__ __forceinline__ float bf2f(unsigned short h) {
  return __uint_as_float(((unsigned)h) << 16);
}

// ---------------- weight prep ----------------
// in [L][K][N] f32 -> out [L][N][K] bf16 (out pre-offset; outL = per-layer out stride in elems)
__global__ void k_wt(const float* __restrict__ in, unsigned short* __restrict__ out,
                     int K, int N, int outL, int total) {
  int idx = blockIdx.x * 256 + threadIdx.x;
  if (idx >= total) return;
  int kn = K * N;
  int l = idx / kn, r = idx - l * kn;
  int k = r / N, n = r - k * N;
  out[(size_t)l * outL + (size_t)n * K + k] = f2bf(in[idx]);
}

// deconv_w [oc][ic][2][2][2] f32 -> Wt_dc[(tap*256+oc)][ic] bf16
__global__ void k_wdc(const float* __restrict__ in, unsigned short* __restrict__ out) {
  int idx = blockIdx.x * 256 + threadIdx.x;      // 524288
  int n = idx >> 8, k = idx & 255;
  out[idx] = f2bf(in[((size_t)(n & 255)) * 2048 + k * 8 + (n >> 8)]);
}

// conv3_w [oc][ic][27] f32 -> wc3[tap][oc][ic] bf16
__global__ void k_wc3(const float* __restrict__ W, unsigned short* __restrict__ T) {
  int idx = blockIdx.x * 256 + threadIdx.x;      // 1327104 = 27*192*256
  int tap = idx / 49152;
  int rem = idx - tap * 49152;
  int oc = rem >> 8, ic = rem & 255;
  T[idx] = f2bf(W[(oc * 256 + ic) * 27 + tap]);
}

__global__ void k_cvt(const float* __restrict__ in, unsigned short* __restrict__ out, int n) {
  int i = blockIdx.x * 256 + threadIdx.x;
  if (i < n) out[i] = f2bf(in[i]);
}

// W_tc [256][768] f32 -> [768][256] f32 (for k_vf)
__global__ void k_wtct(const float* __restrict__ W, float* __restrict__ T) {
  int idx = blockIdx.x * 256 + threadIdx.x;      // 196608
  int k = idx >> 8, o = idx & 255;
  T[idx] = W[o * 768 + k];
}

// ---------------- restore + cam_x (output 2) ----------------
__global__ void k_restore(const float* __restrict__ cx, const int* __restrict__ ids,
                          const float* __restrict__ mtok, float* __restrict__ out) {
  int idx = blockIdx.x * 256 + threadIdx.x;      // 811008 = 6*768*176
  int p = idx % 176;
  int r = idx / 176;
  int ch = r % 768;
  int c = r / 768;
  int id = ids[c * 176 + p];
  out[idx] = (id < 44) ? cx[((size_t)(c * 44 + id)) * 768 + ch] : mtok[ch];
}

// ---------------- vf / feat: relu(camx @ W_tc^T + b) + embeds -> bf16 ----------------
__global__ __launch_bounds__(256) void k_vf(const float* __restrict__ camx, const float* __restrict__ WtT,
                                            const float* __restrict__ btc, const float* __restrict__ cemb,
                                            const float* __restrict__ lemb, unsigned short* __restrict__ featb) {
  __shared__ float sa[768];
  int blk = blockIdx.x;                          // c*176 + p
  int c = blk / 176, p = blk - c * 176;
  int t = threadIdx.x;
  for (int i = t; i < 768; i += 256) sa[i] = camx[((size_t)(c * 768 + i)) * 176 + p];
  __syncthreads();
  float acc = 0.f;
  for (int k = 0; k < 768; ++k) acc += sa[k] * WtT[k * 256 + t];
  featb[(size_t)blk * 256 + t] = f2bf(fmaxf(acc + btc[t], 0.f) + cemb[c * 256 + t] + lemb[t]);
}

// ---------------- bf16 MFMA GEMM, A bf16 [M][lda], B pre-transposed [N][K] bf16 ----------------
// bias split: col<n1 -> bias[col], else bias2[col-n1]
// mode 0: f32 out Cf; mode 2: bf16 out Cb (relu applies); mode 1: deconv scatter into Cb
__global__ __launch_bounds__(256) void k_gemm(
    const unsigned short* __restrict__ A, int M, int lda,
    const unsigned short* __restrict__ Bt, int K, int N,
    const float* __restrict__ bias, const float* __restrict__ bias2, int n1, int relu,
    float* __restrict__ Cf, unsigned short* __restrict__ Cb, int ldc, int mode) {
  __shared__ short sA[128 * 40];
  const int t = threadIdx.x;
  const int l = t & 63, w = t >> 6;
  const int lo = l & 15, kg = l >> 4;
  const int row0 = blockIdx.x * 128, n0 = blockIdx.y * 64;
  const s16x8 bz = {0, 0, 0, 0, 0, 0, 0, 0};
  f32x4 acc[2][4] = {};
  s16x8 bc[4], bn[4];
#pragma unroll
  for (int nb = 0; nb < 4; ++nb) {
    int n = n0 + nb * 16 + lo;
    bc[nb] = (n < N) ? *(const s16x8*)&Bt[(size_t)n * K + kg * 8] : bz;
  }
  const int stR = t >> 1, stH = t & 1;
  for (int kc = 0; kc < K; kc += 32) {
    const bool pf = (kc + 32 < K);
    if (pf) {
#pragma unroll
      for (int nb = 0; nb < 4; ++nb) {
        int n = n0 + nb * 16 + lo;
        bn[nb] = (n < N) ? *(const s16x8*)&Bt[(size_t)n * K + kc + 32 + kg * 8] : bz;
      }
    }
    __syncthreads();
    {
      int r = row0 + stR;
      uint4 v0 = {0u, 0u, 0u, 0u}, v1 = {0u, 0u, 0u, 0u};
      if (r < M) {
        const unsigned short* src = A + (size_t)r * lda + kc + stH * 16;
        v0 = *(const uint4*)src;
        v1 = *(const uint4*)(src + 8);
      }
      *(uint4*)&sA[stR * 40 + stH * 16] = v0;
      *(uint4*)&sA[stR * 40 + stH * 16 + 8] = v1;
    }
    __syncthreads();
    s16x8 a0 = *(const s16x8*)&sA[(w * 32 + lo) * 40 + kg * 8];
    s16x8 a1 = *(const s16x8*)&sA[(w * 32 + 16 + lo) * 40 + kg * 8];
#pragma unroll
    for (int nb = 0; nb < 4; ++nb) {
      acc[0][nb] = __builtin_amdgcn_mfma_f32_16x16x32_bf16(a0, bc[nb], acc[0][nb], 0, 0, 0);
      acc[1][nb] = __builtin_amdgcn_mfma_f32_16x16x32_bf16(a1, bc[nb], acc[1][nb], 0, 0, 0);
    }
    if (pf) {
#pragma unroll
      for (int nb = 0; nb < 4; ++nb) bc[nb] = bn[nb];
    }
  }
#pragma unroll
  for (int m = 0; m < 2; ++m)
#pragma unroll
    for (int nb = 0; nb < 4; ++nb)
#pragma unroll
      for (int r = 0; r < 4; ++r) {
        int row = row0 + w * 32 + m * 16 + (kg << 2) + r;
        int col = n0 + nb * 16 + lo;
        if (row < M && col < N) {
          float v = acc[m][nb][r];
          if (bias) v += (col < n1) ? bias[col] : bias2[col - n1];
          if (relu) v = fmaxf(v, 0.f);
          if (mode == 0) {
            Cf[(size_t)row * ldc + col] = v;
          } else if (mode == 2) {
            Cb[(size_t)row * ldc + col] = f2bf(v);
          } else {
            int tap = col >> 8, oc = col & 255;
            int z = row / 2500, rr = row - z * 2500;
            int hy = rr / 50, wx = rr - hy * 50;
            int t1 = tap >> 2, t2 = (tap >> 1) & 1, t3 = tap & 1;
            int od = 2 * wx + 1 - t1, oh = 2 * hy + 1 - t2, ow = 2 * z + 1 - t3;
            Cb[((size_t)((od * 100 + oh) * 16 + ow)) * 256 + oc] = f2bf(v);
          }
        }
      }
}

// ---------------- softmax + bilinear sampling + aggregate (-> bf16 agg) ----------------
__global__ __launch_bounds__(256) void k_sample(const float* __restrict__ oa,
                                                const float* __restrict__ val,
                                                unsigned short* __restrict__ aggb) {
  __shared__ float sl[96], sw[96];
  int n = blockIdx.x, t = threadIdx.x;
  if (t < 96) sl[t] = oa[(size_t)n * 288 + 192 + t];
  __syncthreads();
  if (t < 8) {
    float mx = -1e30f;
    for (int j = 0; j < 12; ++j) mx = fmaxf(mx, sl[t * 12 + j]);
    float s = 0.f;
    for (int j = 0; j < 12; ++j) s += __expf(sl[t * 12 + j] - mx);
    float inv = 1.f / s;
    for (int j = 0; j < 12; ++j) sw[t * 12 + j] = __expf(sl[t * 12 + j] - mx) * inv;
  }
  __syncthreads();
  int h = t >> 5, d = t & 31;
  float xr = ((float)(n % 50) + 0.5f) * (22.0f / 50.0f) - 0.5f;
  float yr = ((float)((n / 50) % 50) + 0.5f) * (8.0f / 50.0f) - 0.5f;
  float acc = 0.f;
  const float* offn = oa + (size_t)n * 288 + h * 24;  // [h][c][p][2]
  const float* vbh = val + (size_t)h * 32 + d;
#pragma unroll
  for (int c = 0; c < 6; ++c)
#pragma unroll
    for (int p2 = 0; p2 < 2; ++p2) {
      float x = xr + offn[(c * 2 + p2) * 2];
      float y = yr + offn[(c * 2 + p2) * 2 + 1];
      float x0 = floorf(x), y0 = floorf(y);
      float wx = x - x0, wy = y - y0;
      int ix0 = min(max((int)x0, 0), 21), ix1 = min(max((int)x0 + 1, 0), 21);
      int iy0 = min(max((int)y0, 0), 7), iy1 = min(max((int)y0 + 1, 0), 7);
      const float* vb = vbh + (size_t)c * 176 * 256;
      float v00 = vb[(size_t)(iy0 * 22 + ix0) * 256];
      float v01 = vb[(size_t)(iy0 * 22 + ix1) * 256];
      float v10 = vb[(size_t)(iy1 * 22 + ix0) * 256];
      float v11 = vb[(size_t)(iy1 * 22 + ix1) * 256];
      float bil = (1.f - wx) * (1.f - wy) * v00 + wx * (1.f - wy) * v01 +
                  (1.f - wx) * wy * v10 + wx * wy * v11;
      acc += sw[h * 12 + c * 2 + p2] * bil;
    }
  aggb[(size_t)n * 256 + t] = f2bf(acc);
}

// ---------------- residual + LayerNorm(256): writes q f32 AND qb bf16 ----------------
__global__ __launch_bounds__(256) void k_addln(float* __restrict__ q, const float* __restrict__ p,
                                               const float* __restrict__ g, const float* __restrict__ b,
                                               unsigned short* __restrict__ qb) {
  __shared__ float red[8];
  int n = blockIdx.x, t = threadIdx.x;
  float x = q[(size_t)n * 256 + t] + p[(size_t)n * 256 + t];
  float s1 = x, s2 = x * x;
#pragma unroll
  for (int o = 32; o >= 1; o >>= 1) {
    s1 += __shfl_xor(s1, o, 64);
    s2 += __shfl_xor(s2, o, 64);
  }
  int w = t >> 6;
  if ((t & 63) == 0) { red[w * 2] = s1; red[w * 2 + 1] = s2; }
  __syncthreads();
  s1 = red[0] + red[2] + red[4] + red[6];
  s2 = red[1] + red[3] + red[5] + red[7];
  float mean = s1 * (1.0f / 256.0f);
  float var = s2 * (1.0f / 256.0f) - mean * mean;
  float y = (x - mean) * rsqrtf(var + 1e-5f) * g[t] + b[t];
  q[(size_t)n * 256 + t] = y;
  qb[(size_t)n * 256 + t] = f2bf(y);
}

// ---------------- GroupNorm 1 (256 ch, 16 groups) over x1 [160000][256] bf16 ----------------
__global__ __launch_bounds__(256) void k_gnstat1(const unsigned short* __restrict__ X, float* __restrict__ part) {
  __shared__ float s1[256], s2[256];
  int b = blockIdx.x, t = threadIdx.x;   // 2500 blocks * 16384 elems
  unsigned base = (unsigned)b * 16384u + (unsigned)t;
  float a = 0.f, q = 0.f;
  for (int i = 0; i < 64; ++i) { float v = bf2f(X[base + (unsigned)i * 256u]); a += v; q += v * v; }
  s1[t] = a; s2[t] = q;
  __syncthreads();
  for (int s = 8; s > 0; s >>= 1) {
    if ((t & 15) < s) { s1[t] += s1[t + s]; s2[t] += s2[t + s]; }
    __syncthreads();
  }
  if ((t & 15) == 0) {
    part[(t >> 4) * 2500 + b] = s1[t];
    part[40000 + (t >> 4) * 2500 + b] = s2[t];
  }
}

__global__ __launch_bounds__(256) void k_gnred1(const float* __restrict__ part, float* __restrict__ gmv) {
  __shared__ float s1[256], s2[256];
  int g = blockIdx.x, t = threadIdx.x;   // 16 blocks
  float a = 0.f, q = 0.f;
  for (int i = t; i < 2500; i += 256) { a += part[g * 2500 + i]; q += part[40000 + g * 2500 + i]; }
  s1[t] = a; s2[t] = q;
  __syncthreads();
  for (int s = 128; s > 0; s >>= 1) {
    if (t < s) { s1[t] += s1[t + s]; s2[t] += s2[t + s]; }
    __syncthreads();
  }
  if (t == 0) {
    float m = s1[0] / 2560000.0f;
    float v = s2[0] / 2560000.0f - m * m;
    gmv[2 * g] = m; gmv[2 * g + 1] = rsqrtf(v + 1e-5f);
  }
}

__global__ __launch_bounds__(256) void k_gnapply1(unsigned short* __restrict__ X, const float* __restrict__ gmv,
                                                  const float* __restrict__ g, const float* __restrict__ b) {
  for (unsigned idx = blockIdx.x * 256 + threadIdx.x; idx < 40960000u; idx += gridDim.x * 256) {
    int oc = idx & 255, grp = oc >> 4;
    float v = bf2f(X[idx]);
    v = (v - gmv[grp * 2]) * gmv[grp * 2 + 1] * g[oc] + b[oc];
    X[idx] = f2bf(fmaxf(v, 0.f));
  }
}

// ---------------- conv3 3x3x3 (256->192) ----------------
// X slab in LDS (padded, conflict-free); weights double-buffered in LDS with
// XOR-swizzled granules: element (oc, kgrp) at granule 4*oc + (kgrp ^ (oc&3)).
// Global weight loads coalesced (kgs-fastest); LDS writes contiguous; reads uniform 8 words/bank.
// One barrier per tap; T14 issue-early/write-late prefetch; bijective XCD-chunked swizzle.
__global__ __launch_bounds__(256, 2) void k_conv3(const unsigned short* __restrict__ X,
                                                  const unsigned short* __restrict__ Wp,
                                                  unsigned short* __restrict__ Y) {
  __shared__ short sX[4 * 543 * 8];    // 34.75 KB
  __shared__ short sW[2][768 * 8];     // 24.58 KB
  // bijective XCD swizzle over 1300 blocks (q=162, r=4)
  int bid = blockIdx.x;
  int xcd = bid & 7, idx = bid >> 3;
  int swz = (xcd < 4 ? xcd * 163 : 652 + (xcd - 4) * 162) + idx;
  const int od = swz / 13;
  const int oh0 = (swz - od * 13) * 8;
  const int t = threadIdx.x;
  const int l = t & 63, w = t >> 6;
  const int kg = l >> 4, lo = l & 15;
  f32x4 acc[8][3] = {};
  // per-thread staging element mapping (3 elements of 768 = 192 oc x 4 kgs)
  const int oc0 = t >> 2, oc1 = (t + 256) >> 2, oc2 = (t + 512) >> 2;
  const int kgs = t & 3;
  const int g0 = 4 * oc0 + (kgs ^ (oc0 & 3));
  const int g1 = 4 * oc1 + (kgs ^ (oc1 & 3));
  const int g2 = 4 * oc2 + (kgs ^ (oc2 & 3));
  // per-thread MFMA b-fragment read offsets (thread-constant)
  int woff[3];
#pragma unroll
  for (int nb = 0; nb < 3; ++nb)
    woff[nb] = (4 * (w * 48 + nb * 16 + lo) + (kg ^ (lo & 3))) * 8;

  int cur = 0;
  for (int chunk = 0; chunk < 8; ++chunk) {
    // stage slab: 540 pos x 4 kgrp uint4 (sX dead: prev tap loop ended with barrier)
#pragma unroll
    for (int i = 0; i < 9; ++i) {
      int e = t + i * 256;
      if (e < 2160) {
        int pos = e >> 2, ks = e & 3;
        int sd = pos / 180, r2 = pos - sd * 180;
        int sh = r2 / 18, sw_ = r2 - sh * 18;
        int gd = od + sd - 1, gh = oh0 + sh - 1, gw = sw_ - 1;
        uint4 v = {0u, 0u, 0u, 0u};
        if ((unsigned)gd < 100u && (unsigned)gh < 100u && (unsigned)gw < 16u)
          v = *(const uint4*)&X[((size_t)((gd * 100 + gh) * 16 + gw)) * 256 + chunk * 32 + ks * 8];
        *(uint4*)&sX[(ks * 543 + pos) * 8] = v;
      }
    }
    if (chunk == 0) {  // initial weights (tap 0, chunk 0) into buf 0
      *(uint4*)&sW[0][g0 * 8] = *(const uint4*)&Wp[(size_t)oc0 * 256 + kgs * 8];
      *(uint4*)&sW[0][g1 * 8] = *(const uint4*)&Wp[(size_t)oc1 * 256 + kgs * 8];
      *(uint4*)&sW[0][g2 * 8] = *(const uint4*)&Wp[(size_t)oc2 * 256 + kgs * 8];
    }
    __syncthreads();
    for (int tap = 0; tap < 27; ++tap) {
      int ntap = tap + 1, nch = chunk;
      if (ntap == 27) { ntap = 0; ++nch; }
      const bool pf = (nch < 8);
      uint4 wr0, wr1, wr2;
      if (pf) {  // issue-early (coalesced 64B per 4 threads)
        const unsigned short* wb = Wp + (size_t)ntap * 49152 + nch * 32 + kgs * 8;
        wr0 = *(const uint4*)&wb[(size_t)oc0 * 256];
        wr1 = *(const uint4*)&wb[(size_t)oc1 * 256];
        wr2 = *(const uint4*)&wb[(size_t)oc2 * 256];
      }
      const int t1 = tap / 9, tr = tap - t1 * 9, t2 = tr / 3, t3 = tr - t2 * 3;
      const short* swc = sW[cur];
      s16x8 b0 = *(const s16x8*)&swc[woff[0]];
      s16x8 b1 = *(const s16x8*)&swc[woff[1]];
      s16x8 b2 = *(const s16x8*)&swc[woff[2]];
#pragma unroll
      for (int m = 0; m < 8; ++m) {
        int pos = t1 * 180 + (m + t2) * 18 + lo + t3;
        s16x8 a = *(const s16x8*)&sX[(kg * 543 + pos) * 8];
        acc[m][0] = __builtin_amdgcn_mfma_f32_16x16x32_bf16(a, b0, acc[m][0], 0, 0, 0);
        acc[m][1] = __builtin_amdgcn_mfma_f32_16x16x32_bf16(a, b1, acc[m][1], 0, 0, 0);
        acc[m][2] = __builtin_amdgcn_mfma_f32_16x16x32_bf16(a, b2, acc[m][2], 0, 0, 0);
      }
      if (pf) {  // write-late into the other buffer
        short* swn = sW[cur ^ 1];
        *(uint4*)&swn[g0 * 8] = wr0;
        *(uint4*)&swn[g1 * 8] = wr1;
        *(uint4*)&swn[g2 * 8] = wr2;
      }
      cur ^= 1;
      __syncthreads();
    }
  }
#pragma unroll
  for (int m = 0; m < 8; ++m) {
    int oh = oh0 + m;
    if (oh < 100) {
#pragma unroll
      for (int nb = 0; nb < 3; ++nb)
#pragma unroll
        for (int r = 0; r < 4; ++r) {
          int oc = w * 48 + nb * 16 + lo;
          int ow = (kg << 2) + r;
          Y[(size_t)oc * 160000 + (size_t)((od * 100 + oh) * 16) + ow] = f2bf(acc[m][nb][r]);
        }
    }
  }
}

// ---------------- GroupNorm 2 (192 ch, 16 groups) over [192][160000] bf16 ----------------
__global__ __launch_bounds__(256) void k_gnstat2(const unsigned short* __restrict__ X, float* __restrict__ part) {
  __shared__ float s1[256], s2[256];
  int b = blockIdx.x, t = threadIdx.x;   // 1920 blocks: ch = b/10, part p = b%10
  int ch = b / 10, pp = b - ch * 10;
  unsigned base = (unsigned)ch * 160000u + (unsigned)pp * 16000u;
  float a = 0.f, q = 0.f;
  for (int i = t; i < 16000; i += 256) { float v = bf2f(X[base + i]); a += v; q += v * v; }
  s1[t] = a; s2[t] = q;
  __syncthreads();
  for (int s = 128; s > 0; s >>= 1) {
    if (t < s) { s1[t] += s1[t + s]; s2[t] += s2[t + s]; }
    __syncthreads();
  }
  if (t == 0) { part[80000 + ch * 10 + pp] = s1[0]; part[81920 + ch * 10 + pp] = s2[0]; }
}

__global__ __launch_bounds__(256) void k_gnred2(const float* __restrict__ part, float* __restrict__ gmv) {
  __shared__ float s1[256], s2[256];
  int g = blockIdx.x, t = threadIdx.x;   // 16 blocks, 120 partials each
  float a = (t < 120) ? part[80000 + g * 120 + t] : 0.f;
  float q = (t < 120) ? part[81920 + g * 120 + t] : 0.f;
  s1[t] = a; s2[t] = q;
  __syncthreads();
  for (int s = 128; s > 0; s >>= 1) {
    if (t < s) { s1[t] += s1[t + s]; s2[t] += s2[t + s]; }
    __syncthreads();
  }
  if (t == 0) {
    float m = s1[0] / 1920000.0f;
    float v = s2[0] / 1920000.0f - m * m;
    gmv[2 * g] = m; gmv[2 * g + 1] = rsqrtf(v + 1e-5f);
  }
}

__global__ __launch_bounds__(256) void k_gnapply2(const unsigned short* __restrict__ X, const float* __restrict__ gmv,
                                                  const float* __restrict__ g, const float* __restrict__ b,
                                                  float* __restrict__ out) {
  for (unsigned idx = blockIdx.x * 256 + threadIdx.x; idx < 30720000u; idx += gridDim.x * 256) {
    unsigned oc = idx / 160000u;
    unsigned grp = oc / 12u;
    float v = bf2f(X[idx]);
    v = (v - gmv[grp * 2]) * gmv[grp * 2 + 1] * g[oc] + b[oc];
    out[idx] = fmaxf(v, 0.f);
  }
}

// ---------------- host ----------------
static inline dim3 gemm_grid(int M, int N) { return dim3((M + 127) / 128, (N + 63) / 64); }

extern "C" void kernel_launch(void* const* d_in, const int* in_sizes, int n_in,
                              void* d_out, int out_size, void* d_ws, size_t ws_size,
                              hipStream_t stream) {
  const float* camera_x = (const float*)d_in[0];
  const int* ids = (const int*)d_in[1];
  const float* mask_tok = (const float*)d_in[4];
  const float* vol_emb = (const float*)d_in[5];
  const float* W_tc = (const float*)d_in[6];
  const float* b_tc = (const float*)d_in[7];
  const float* cams_emb = (const float*)d_in[8];
  const float* lvl_emb = (const float*)d_in[9];
  const float* W_off = (const float*)d_in[10];
  const float* b_off = (const float*)d_in[11];
  const float* W_att = (const float*)d_in[12];
  const float* b_att = (const float*)d_in[13];
  const float* W_val = (const float*)d_in[14];
  const float* b_val = (const float*)d_in[15];
  const float* W_out = (const float*)d_in[16];
  const float* b_out = (const float*)d_in[17];
  const float* ln1_g = (const float*)d_in[18];
  const float* ln1_b = (const float*)d_in[19];
  const float* W_ff1 = (const float*)d_in[20];
  const float* b_ff1 = (const float*)d_in[21];
  const float* W_ff2 = (const float*)d_in[22];
  const float* b_ff2 = (const float*)d_in[23];
  const float* ln2_g = (const float*)d_in[24];
  const float* ln2_b = (const float*)d_in[25];
  const float* deconv_w = (const float*)d_in[26];
  const float* gn1_g = (const float*)d_in[27];
  const float* gn1_b = (const float*)d_in[28];
  const float* conv3_w = (const float*)d_in[29];
  const float* gn2_g = (const float*)d_in[30];
  const float* gn2_b = (const float*)d_in[31];

  char* ws = (char*)d_ws;
  float* q             = (float*)(ws + 0);                      // 20.48 MB
  unsigned short* qb   = (unsigned short*)(ws + 20480000);      // 10.24 MB
  float* proj          = (float*)(ws + 30720000);               // 20.48 MB
  float* oa            = (float*)(ws + 51200000);               // 23.04 MB
  unsigned short* aggb = (unsigned short*)(ws + 74240000);      // 10.24 MB
  unsigned short* ffhb = (unsigned short*)(ws + 84480000);      // 20.48 MB
  float* val           = (float*)(ws + 104960000);              // 1.08 MB
  unsigned short* featb= (unsigned short*)(ws + 106041344);     // 0.54 MB
  unsigned short* x1bf = (unsigned short*)(ws + 30720000);      // 81.92 MB (aliases decoder scratch, dead post-decoder)
  unsigned short* c3   = (unsigned short*)(ws + 112640000);     // 61.44 MB
  unsigned short* Wt_val = (unsigned short*)(ws + 174080000);   // 393216 B
  unsigned short* Wt_oa  = (unsigned short*)(ws + 174473216);   // 442368 B
  unsigned short* Wt_out = (unsigned short*)(ws + 174915584);   // 393216 B
  unsigned short* Wt_ff1 = (unsigned short*)(ws + 175308800);   // 786432 B
  unsigned short* Wt_ff2 = (unsigned short*)(ws + 176095232);   // 786432 B
  unsigned short* Wt_dc  = (unsigned short*)(ws + 176881664);   // 1048576 B
  unsigned short* wc3    = (unsigned short*)(ws + 177930240);   // 2654208 B
  float* part = (float*)(ws + 180584448);                       // 336 KB
  float* gmv1 = (float*)(ws + 180920320);
  float* gmv2 = (float*)(ws + 180920448);
  float* wtcT = (float*)(ws + 180920576);                       // 786432 B

  float* out_x = (float*)d_out;
  float* out_camx = out_x + 30720000;

  // weight prep
  k_wtct<<<768, 256, 0, stream>>>(W_tc, wtcT);
  k_wt<<<(3 * 65536 + 255) / 256, 256, 0, stream>>>(W_val, Wt_val, 256, 256, 65536, 3 * 65536);
  k_wt<<<(3 * 49152 + 255) / 256, 256, 0, stream>>>(W_off, Wt_oa, 256, 192, 73728, 3 * 49152);
  k_wt<<<(3 * 24576 + 255) / 256, 256, 0, stream>>>(W_att, Wt_oa + 192 * 256, 256, 96, 73728, 3 * 24576);
  k_wt<<<(3 * 65536 + 255) / 256, 256, 0, stream>>>(W_out, Wt_out, 256, 256, 65536, 3 * 65536);
  k_wt<<<(3 * 131072 + 255) / 256, 256, 0, stream>>>(W_ff1, Wt_ff1, 256, 512, 131072, 3 * 131072);
  k_wt<<<(3 * 131072 + 255) / 256, 256, 0, stream>>>(W_ff2, Wt_ff2, 512, 256, 131072, 3 * 131072);
  k_wdc<<<2048, 256, 0, stream>>>(deconv_w, Wt_dc);
  k_wc3<<<5184, 256, 0, stream>>>(conv3_w, wc3);

  k_restore<<<3168, 256, 0, stream>>>(camera_x, ids, mask_tok, out_camx);
  k_vf<<<1056, 256, 0, stream>>>(out_camx, wtcT, b_tc, cams_emb, lvl_emb, featb);
  hipMemcpyAsync(q, vol_emb, (size_t)20000 * 256 * 4, hipMemcpyDeviceToDevice, stream);
  k_cvt<<<20000, 256, 0, stream>>>(vol_emb, qb, 5120000);

  for (int lyr = 0; lyr < 3; ++lyr) {
    k_gemm<<<gemm_grid(1056, 256), 256, 0, stream>>>(featb, 1056, 256, Wt_val + lyr * 65536, 256, 256,
                                                     b_val + lyr * 256, nullptr, 256, 0, val, nullptr, 256, 0);
    k_gemm<<<gemm_grid(20000, 288), 256, 0, stream>>>(qb, 20000, 256, Wt_oa + lyr * 73728, 256, 288,
                                                      b_off + lyr * 192, b_att + lyr * 96, 192, 0,
                                                      oa, nullptr, 288, 0);
    k_sample<<<20000, 256, 0, stream>>>(oa, val, aggb);
    k_gemm<<<gemm_grid(20000, 256), 256, 0, stream>>>(aggb, 20000, 256, Wt_out + lyr * 65536, 256, 256,
                                                      b_out + lyr * 256, nullptr, 256, 0, proj, nullptr, 256, 0);
    k_addln<<<20000, 256, 0, stream>>>(q, proj, ln1_g + lyr * 256, ln1_b + lyr * 256, qb);
    k_gemm<<<gemm_grid(20000, 512), 256, 0, stream>>>(qb, 20000, 256, Wt_ff1 + lyr * 131072, 256, 512,
                                                      b_ff1 + lyr * 512, nullptr, 512, 1, nullptr, ffhb, 512, 2);
    k_gemm<<<gemm_grid(20000, 256), 256, 0, stream>>>(ffhb, 20000, 512, Wt_ff2 + lyr * 131072, 512, 256,
                                                      b_ff2 + lyr * 256, nullptr, 256, 0, proj, nullptr, 256, 0);
    k_addln<<<20000, 256, 0, stream>>>(q, proj, ln2_g + lyr * 256, ln2_b + lyr * 256, qb);
  }

  // deconv: all 8 taps in one GEMM (N = 2048), scattered bf16 output
  k_gemm<<<gemm_grid(20000, 2048), 256, 0, stream>>>(qb, 20000, 256, Wt_dc, 256, 2048,
                                                     nullptr, nullptr, 2048, 0, nullptr, x1bf, 256, 1);

  k_gnstat1<<<2500, 256, 0, stream>>>(x1bf, part);
  k_gnred1<<<16, 256, 0, stream>>>(part, gmv1);
  k_gnapply1<<<2048, 256, 0, stream>>>(x1bf, gmv1, gn1_g, gn1_b);

  k_conv3<<<1300, 256, 0, stream>>>(x1bf, wc3, c3);

  k_gnstat2<<<1920, 256, 0, stream>>>(c3, part);
  k_gnred2<<<16, 256, 0, stream>>>(part, gmv2);
  k_gnapply2<<<2048, 256, 0, stream>>>(c3, gmv2, gn2_g, gn2_b, out_x);
}

// Round 6
// 1353.201 us; speedup vs baseline: 2.0100x; 1.1176x over previous
//
#include <hip/hip_runtime.h>
#include <stdint.h>

typedef __attribute__((ext_vector_type(8))) short s16x8;
typedef __attribute__((ext_vector_type(4))) float f32x4;

static __device__ __forceinline__ unsigned short f2bf(float f) {
  unsigned u = __float_as_uint(f);
  u += 0x7FFFu + ((u >> 16) & 1u);
  return (unsigned short)(u >> 16);
}
static __device__ __forceinline__ float bf2f(unsigned short h) {
  return __uint_as_float(((unsigned)h) << 16);
}
static __device__ __forceinline__ void sum8(uint4 u, float& a, float& q) {
  unsigned w[4] = {u.x, u.y, u.z, u.w};
#pragma unroll
  for (int i = 0; i < 4; ++i) {
    float v0 = __uint_as_float((w[i] & 0xFFFFu) << 16);
    float v1 = __uint_as_float(w[i] & 0xFFFF0000u);
    a += v0 + v1;
    q += v0 * v0 + v1 * v1;
  }
}

// ---------------- weight prep ----------------
// in [L][K][N] f32 -> out [L][N][K] bf16
__global__ void k_wt(const float* __restrict__ in, unsigned short* __restrict__ out,
                     int K, int N, int outL, int total) {
  int idx = blockIdx.x * 256 + threadIdx.x;
  if (idx >= total) return;
  int kn = K * N;
  int l = idx / kn, r = idx - l * kn;
  int k = r / N, n = r - k * N;
  out[(size_t)l * outL + (size_t)n * K + k] = f2bf(in[idx]);
}

// deconv_w [oc][ic][2][2][2] f32 -> Wt_dc[(tap*256+oc)][ic] bf16
__global__ void k_wdc(const float* __restrict__ in, unsigned short* __restrict__ out) {
  int idx = blockIdx.x * 256 + threadIdx.x;      // 524288
  int n = idx >> 8, k = idx & 255;
  out[idx] = f2bf(in[((size_t)(n & 255)) * 2048 + k * 8 + (n >> 8)]);
}

// conv3_w [oc][ic][27] f32 -> per-fragment pack:
// w3[((tap*8+chunk)*12 + ocblk)*64 + lane][8], lane = ((ic>>3)&3)*16 + (oc&15), j = ic&7
__global__ void k_wc3(const float* __restrict__ W, unsigned short* __restrict__ T) {
  int idx = blockIdx.x * 256 + threadIdx.x;      // 1327104 = 27*192*256
  int tap = idx / 49152;
  int rem = idx - tap * 49152;
  int oc = rem >> 8, ic = rem & 255;
  int chunk = ic >> 5, kg = (ic >> 3) & 3, j = ic & 7;
  int ocblk = oc >> 4, lo = oc & 15;
  size_t frag = (size_t)(tap * 8 + chunk) * 12 + ocblk;
  T[(frag * 64 + kg * 16 + lo) * 8 + j] = f2bf(W[(oc * 256 + ic) * 27 + tap]);
}

__global__ void k_cvt(const float* __restrict__ in, unsigned short* __restrict__ out, int n) {
  int i = blockIdx.x * 256 + threadIdx.x;
  if (i < n) out[i] = f2bf(in[i]);
}

// W_tc [256][768] f32 -> [768][256] f32 (for k_vf)
__global__ void k_wtct(const float* __restrict__ W, float* __restrict__ T) {
  int idx = blockIdx.x * 256 + threadIdx.x;      // 196608
  int k = idx >> 8, o = idx & 255;
  T[idx] = W[o * 768 + k];
}

// ---------------- restore + cam_x (output 2) ----------------
__global__ void k_restore(const float* __restrict__ cx, const int* __restrict__ ids,
                          const float* __restrict__ mtok, float* __restrict__ out) {
  int idx = blockIdx.x * 256 + threadIdx.x;      // 811008 = 6*768*176
  int p = idx % 176;
  int r = idx / 176;
  int ch = r % 768;
  int c = r / 768;
  int id = ids[c * 176 + p];
  out[idx] = (id < 44) ? cx[((size_t)(c * 44 + id)) * 768 + ch] : mtok[ch];
}

// ---------------- vf / feat: relu(camx @ W_tc^T + b) + embeds -> bf16 ----------------
__global__ __launch_bounds__(256) void k_vf(const float* __restrict__ camx, const float* __restrict__ WtT,
                                            const float* __restrict__ btc, const float* __restrict__ cemb,
                                            const float* __restrict__ lemb, unsigned short* __restrict__ featb) {
  __shared__ float sa[768];
  int blk = blockIdx.x;                          // c*176 + p
  int c = blk / 176, p = blk - c * 176;
  int t = threadIdx.x;
  for (int i = t; i < 768; i += 256) sa[i] = camx[((size_t)(c * 768 + i)) * 176 + p];
  __syncthreads();
  float acc = 0.f;
  for (int k = 0; k < 768; ++k) acc += sa[k] * WtT[k * 256 + t];
  featb[(size_t)blk * 256 + t] = f2bf(fmaxf(acc + btc[t], 0.f) + cemb[c * 256 + t] + lemb[t]);
}

// ---------------- bf16 MFMA GEMM, A bf16 [M][lda], B pre-transposed [N][K] bf16 ----------------
__global__ __launch_bounds__(256) void k_gemm(
    const unsigned short* __restrict__ A, int M, int lda,
    const unsigned short* __restrict__ Bt, int K, int N,
    const float* __restrict__ bias, const float* __restrict__ bias2, int n1, int relu,
    float* __restrict__ Cf, unsigned short* __restrict__ Cb, int ldc, int mode) {
  __shared__ short sA[128 * 40];
  const int t = threadIdx.x;
  const int l = t & 63, w = t >> 6;
  const int lo = l & 15, kg = l >> 4;
  const int row0 = blockIdx.x * 128, n0 = blockIdx.y * 64;
  const s16x8 bz = {0, 0, 0, 0, 0, 0, 0, 0};
  f32x4 acc[2][4] = {};
  s16x8 bc[4], bn[4];
#pragma unroll
  for (int nb = 0; nb < 4; ++nb) {
    int n = n0 + nb * 16 + lo;
    bc[nb] = (n < N) ? *(const s16x8*)&Bt[(size_t)n * K + kg * 8] : bz;
  }
  const int stR = t >> 1, stH = t & 1;
  for (int kc = 0; kc < K; kc += 32) {
    const bool pf = (kc + 32 < K);
    if (pf) {
#pragma unroll
      for (int nb = 0; nb < 4; ++nb) {
        int n = n0 + nb * 16 + lo;
        bn[nb] = (n < N) ? *(const s16x8*)&Bt[(size_t)n * K + kc + 32 + kg * 8] : bz;
      }
    }
    __syncthreads();
    {
      int r = row0 + stR;
      uint4 v0 = {0u, 0u, 0u, 0u}, v1 = {0u, 0u, 0u, 0u};
      if (r < M) {
        const unsigned short* src = A + (size_t)r * lda + kc + stH * 16;
        v0 = *(const uint4*)src;
        v1 = *(const uint4*)(src + 8);
      }
      *(uint4*)&sA[stR * 40 + stH * 16] = v0;
      *(uint4*)&sA[stR * 40 + stH * 16 + 8] = v1;
    }
    __syncthreads();
    s16x8 a0 = *(const s16x8*)&sA[(w * 32 + lo) * 40 + kg * 8];
    s16x8 a1 = *(const s16x8*)&sA[(w * 32 + 16 + lo) * 40 + kg * 8];
#pragma unroll
    for (int nb = 0; nb < 4; ++nb) {
      acc[0][nb] = __builtin_amdgcn_mfma_f32_16x16x32_bf16(a0, bc[nb], acc[0][nb], 0, 0, 0);
      acc[1][nb] = __builtin_amdgcn_mfma_f32_16x16x32_bf16(a1, bc[nb], acc[1][nb], 0, 0, 0);
    }
    if (pf) {
#pragma unroll
      for (int nb = 0; nb < 4; ++nb) bc[nb] = bn[nb];
    }
  }
#pragma unroll
  for (int m = 0; m < 2; ++m)
#pragma unroll
    for (int nb = 0; nb < 4; ++nb)
#pragma unroll
      for (int r = 0; r < 4; ++r) {
        int row = row0 + w * 32 + m * 16 + (kg << 2) + r;
        int col = n0 + nb * 16 + lo;
        if (row < M && col < N) {
          float v = acc[m][nb][r];
          if (bias) v += (col < n1) ? bias[col] : bias2[col - n1];
          if (relu) v = fmaxf(v, 0.f);
          if (mode == 0) {
            Cf[(size_t)row * ldc + col] = v;
          } else if (mode == 2) {
            Cb[(size_t)row * ldc + col] = f2bf(v);
          } else {
            int tap = col >> 8, oc = col & 255;
            int z = row / 2500, rr = row - z * 2500;
            int hy = rr / 50, wx = rr - hy * 50;
            int t1 = tap >> 2, t2 = (tap >> 1) & 1, t3 = tap & 1;
            int od = 2 * wx + 1 - t1, oh = 2 * hy + 1 - t2, ow = 2 * z + 1 - t3;
            Cb[((size_t)((od * 100 + oh) * 16 + ow)) * 256 + oc] = f2bf(v);
          }
        }
      }
}

// ---------------- softmax + bilinear sampling + aggregate (-> bf16 agg) ----------------
__global__ __launch_bounds__(256) void k_sample(const float* __restrict__ oa,
                                                const float* __restrict__ val,
                                                unsigned short* __restrict__ aggb) {
  __shared__ float sl[96], sw[96];
  int n = blockIdx.x, t = threadIdx.x;
  if (t < 96) sl[t] = oa[(size_t)n * 288 + 192 + t];
  __syncthreads();
  if (t < 8) {
    float mx = -1e30f;
    for (int j = 0; j < 12; ++j) mx = fmaxf(mx, sl[t * 12 + j]);
    float s = 0.f;
    for (int j = 0; j < 12; ++j) s += __expf(sl[t * 12 + j] - mx);
    float inv = 1.f / s;
    for (int j = 0; j < 12; ++j) sw[t * 12 + j] = __expf(sl[t * 12 + j] - mx) * inv;
  }
  __syncthreads();
  int h = t >> 5, d = t & 31;
  float xr = ((float)(n % 50) + 0.5f) * (22.0f / 50.0f) - 0.5f;
  float yr = ((float)((n / 50) % 50) + 0.5f) * (8.0f / 50.0f) - 0.5f;
  float acc = 0.f;
  const float* offn = oa + (size_t)n * 288 + h * 24;  // [h][c][p][2]
  const float* vbh = val + (size_t)h * 32 + d;
#pragma unroll
  for (int c = 0; c < 6; ++c)
#pragma unroll
    for (int p2 = 0; p2 < 2; ++p2) {
      float x = xr + offn[(c * 2 + p2) * 2];
      float y = yr + offn[(c * 2 + p2) * 2 + 1];
      float x0 = floorf(x), y0 = floorf(y);
      float wx = x - x0, wy = y - y0;
      int ix0 = min(max((int)x0, 0), 21), ix1 = min(max((int)x0 + 1, 0), 21);
      int iy0 = min(max((int)y0, 0), 7), iy1 = min(max((int)y0 + 1, 0), 7);
      const float* vb = vbh + (size_t)c * 176 * 256;
      float v00 = vb[(size_t)(iy0 * 22 + ix0) * 256];
      float v01 = vb[(size_t)(iy0 * 22 + ix1) * 256];
      float v10 = vb[(size_t)(iy1 * 22 + ix0) * 256];
      float v11 = vb[(size_t)(iy1 * 22 + ix1) * 256];
      float bil = (1.f - wx) * (1.f - wy) * v00 + wx * (1.f - wy) * v01 +
                  (1.f - wx) * wy * v10 + wx * wy * v11;
      acc += sw[h * 12 + c * 2 + p2] * bil;
    }
  aggb[(size_t)n * 256 + t] = f2bf(acc);
}

// ---------------- residual + LayerNorm(256): writes q f32 AND qb bf16 ----------------
__global__ __launch_bounds__(256) void k_addln(float* __restrict__ q, const float* __restrict__ p,
                                               const float* __restrict__ g, const float* __restrict__ b,
                                               unsigned short* __restrict__ qb) {
  __shared__ float red[8];
  int n = blockIdx.x, t = threadIdx.x;
  float x = q[(size_t)n * 256 + t] + p[(size_t)n * 256 + t];
  float s1 = x, s2 = x * x;
#pragma unroll
  for (int o = 32; o >= 1; o >>= 1) {
    s1 += __shfl_xor(s1, o, 64);
    s2 += __shfl_xor(s2, o, 64);
  }
  int w = t >> 6;
  if ((t & 63) == 0) { red[w * 2] = s1; red[w * 2 + 1] = s2; }
  __syncthreads();
  s1 = red[0] + red[2] + red[4] + red[6];
  s2 = red[1] + red[3] + red[5] + red[7];
  float mean = s1 * (1.0f / 256.0f);
  float var = s2 * (1.0f / 256.0f) - mean * mean;
  float y = (x - mean) * rsqrtf(var + 1e-5f) * g[t] + b[t];
  q[(size_t)n * 256 + t] = y;
  qb[(size_t)n * 256 + t] = f2bf(y);
}

// ---------------- GroupNorm 1 (256 ch, 16 groups), vectorized uint4 ----------------
__global__ __launch_bounds__(256) void k_gnstat1(const unsigned short* __restrict__ X, float* __restrict__ part) {
  __shared__ float s1[256], s2[256];
  int b = blockIdx.x, t = threadIdx.x;   // 2500 blocks x (64 vox x 256 ch)
  int oc8 = t & 31, v0 = t >> 5;
  float a = 0.f, q = 0.f;
#pragma unroll
  for (int i = 0; i < 8; ++i) {
    int vox = v0 + i * 8;
    uint4 u = *(const uint4*)&X[(size_t)b * 16384 + vox * 256 + oc8 * 8];
    sum8(u, a, q);
  }
  s1[t] = a; s2[t] = q;
  __syncthreads();
  if (t < 128) { s1[t] += s1[t + 128]; s2[t] += s2[t + 128]; }
  __syncthreads();
  if (t < 64) { s1[t] += s1[t + 64]; s2[t] += s2[t + 64]; }
  __syncthreads();
  if (t < 32) { s1[t] += s1[t + 32]; s2[t] += s2[t + 32]; }
  __syncthreads();
  if (t < 16) {
    part[t * 2500 + b] = s1[2 * t] + s1[2 * t + 1];
    part[40000 + t * 2500 + b] = s2[2 * t] + s2[2 * t + 1];
  }
}

__global__ __launch_bounds__(256) void k_gnred1(const float* __restrict__ part, float* __restrict__ gmv) {
  __shared__ float s1[256], s2[256];
  int g = blockIdx.x, t = threadIdx.x;   // 16 blocks
  float a = 0.f, q = 0.f;
  for (int i = t; i < 2500; i += 256) { a += part[g * 2500 + i]; q += part[40000 + g * 2500 + i]; }
  s1[t] = a; s2[t] = q;
  __syncthreads();
  for (int s = 128; s > 0; s >>= 1) {
    if (t < s) { s1[t] += s1[t + s]; s2[t] += s2[t + s]; }
    __syncthreads();
  }
  if (t == 0) {
    float m = s1[0] / 2560000.0f;
    float v = s2[0] / 2560000.0f - m * m;
    gmv[2 * g] = m; gmv[2 * g + 1] = rsqrtf(v + 1e-5f);
  }
}

__global__ __launch_bounds__(256) void k_gnapply1(unsigned short* __restrict__ X, const float* __restrict__ gmv,
                                                  const float* __restrict__ g, const float* __restrict__ b) {
  for (unsigned i = blockIdx.x * 256 + threadIdx.x; i < 5120000u; i += gridDim.x * 256) {
    unsigned e = i * 8u;
    int oc0 = e & 255, grp = oc0 >> 4;
    float mean = gmv[grp * 2], rstd = gmv[grp * 2 + 1];
    float4 g0 = *(const float4*)&g[oc0], g1 = *(const float4*)&g[oc0 + 4];
    float4 b0 = *(const float4*)&b[oc0], b1 = *(const float4*)&b[oc0 + 4];
    uint4 u = *(const uint4*)&X[e];
    unsigned w[4] = {u.x, u.y, u.z, u.w};
    float gg[8] = {g0.x, g0.y, g0.z, g0.w, g1.x, g1.y, g1.z, g1.w};
    float bb[8] = {b0.x, b0.y, b0.z, b0.w, b1.x, b1.y, b1.z, b1.w};
    unsigned o[4];
#pragma unroll
    for (int j = 0; j < 4; ++j) {
      float v0 = __uint_as_float((w[j] & 0xFFFFu) << 16);
      float v1 = __uint_as_float(w[j] & 0xFFFF0000u);
      v0 = fmaxf((v0 - mean) * rstd * gg[2 * j] + bb[2 * j], 0.f);
      v1 = fmaxf((v1 - mean) * rstd * gg[2 * j + 1] + bb[2 * j + 1], 0.f);
      o[j] = (unsigned)f2bf(v0) | ((unsigned)f2bf(v1) << 16);
    }
    *(uint4*)&X[e] = make_uint4(o[0], o[1], o[2], o[3]);
  }
}

// ---------------- conv3 3x3x3 (256->192): sX slab + per-fragment global B, A-reuse over t2 ----
// X: x1 bf16 [vox][256]; Wp: packed fragments; Y: [192][160000] bf16
__global__ __launch_bounds__(256, 2) void k_conv3(const unsigned short* __restrict__ X,
                                                  const unsigned short* __restrict__ Wp,
                                                  unsigned short* __restrict__ Y) {
  __shared__ short sX[4 * 543 * 8];    // 34.75 KB
  // bijective XCD swizzle over 1300 blocks (q=162, r=4)
  int bid = blockIdx.x;
  int xcd = bid & 7, idx = bid >> 3;
  int swz = (xcd < 4 ? xcd * 163 : 652 + (xcd - 4) * 162) + idx;
  const int od = swz / 13;
  const int oh0 = (swz - od * 13) * 8;
  const int t = threadIdx.x;
  const int l = t & 63, w = t >> 6;
  const int kg = l >> 4, lo = l & 15;
  f32x4 acc[8][3] = {};
  s16x8 bc[9], bn[9];
  const unsigned short* Wl = Wp + (size_t)l * 8;   // lane offset within fragment
  const int w3 = w * 3;
  // preload group 0 (chunk 0, t1=0, t3=0 -> taps 0,3,6)
#pragma unroll
  for (int t2 = 0; t2 < 3; ++t2)
#pragma unroll
    for (int nb = 0; nb < 3; ++nb)
      bc[t2 * 3 + nb] = *(const s16x8*)&Wl[(size_t)((t2 * 3 * 8) * 12 + w3 + nb) * 512];

  for (int g = 0; g < 72; ++g) {
    const int chunk = g / 9;
    const int sub = g - chunk * 9;
    const int t1 = sub / 3, t3 = sub - t1 * 3;
    if (sub == 0) {
      __syncthreads();
#pragma unroll
      for (int i = 0; i < 9; ++i) {   // stage slab: 540 pos x 4 kgrp uint4
        int e = t + i * 256;
        if (e < 2160) {
          int pos = e >> 2, ks = e & 3;
          int sd = pos / 180, r2 = pos - sd * 180;
          int sh = r2 / 18, sw_ = r2 - sh * 18;
          int gd = od + sd - 1, gh = oh0 + sh - 1, gw = sw_ - 1;
          uint4 v = {0u, 0u, 0u, 0u};
          if ((unsigned)gd < 100u && (unsigned)gh < 100u && (unsigned)gw < 16u)
            v = *(const uint4*)&X[((size_t)((gd * 100 + gh) * 16 + gw)) * 256 + chunk * 32 + ks * 8];
          *(uint4*)&sX[(ks * 543 + pos) * 8] = v;
        }
      }
      __syncthreads();
    }
    // prefetch next group's 9 fragments (global, coalesced 1024B per fragment per wave)
    const int g1 = g + 1;
    if (g1 < 72) {
      const int c1 = g1 / 9, s1 = g1 - c1 * 9;
      const int t1n = s1 / 3, t3n = s1 - t1n * 3;
#pragma unroll
      for (int t2 = 0; t2 < 3; ++t2)
#pragma unroll
        for (int nb = 0; nb < 3; ++nb)
          bn[t2 * 3 + nb] = *(const s16x8*)&Wl[
              (size_t)(((t1n * 9 + t2 * 3 + t3n) * 8 + c1) * 12 + w3 + nb) * 512];
    }
    // compute: slab row sh feeds t2 in {0,1,2} (m = sh - t2)
    const int abase = kg * 543 + t1 * 180 + lo + t3;
#pragma unroll
    for (int sh = 0; sh < 10; ++sh) {
      s16x8 a = *(const s16x8*)&sX[(abase + sh * 18) * 8];
#pragma unroll
      for (int t2 = 0; t2 < 3; ++t2) {
        const int m = sh - t2;
        if (m >= 0 && m < 8) {
          acc[m][0] = __builtin_amdgcn_mfma_f32_16x16x32_bf16(a, bc[t2 * 3 + 0], acc[m][0], 0, 0, 0);
          acc[m][1] = __builtin_amdgcn_mfma_f32_16x16x32_bf16(a, bc[t2 * 3 + 1], acc[m][1], 0, 0, 0);
          acc[m][2] = __builtin_amdgcn_mfma_f32_16x16x32_bf16(a, bc[t2 * 3 + 2], acc[m][2], 0, 0, 0);
        }
      }
    }
#pragma unroll
    for (int i = 0; i < 9; ++i) bc[i] = bn[i];
  }
#pragma unroll
  for (int m = 0; m < 8; ++m) {
    int oh = oh0 + m;
    if (oh < 100) {
#pragma unroll
      for (int nb = 0; nb < 3; ++nb)
#pragma unroll
        for (int r = 0; r < 4; ++r) {
          int oc = w * 48 + nb * 16 + lo;
          int ow = (kg << 2) + r;
          Y[(size_t)oc * 160000 + (size_t)((od * 100 + oh) * 16) + ow] = f2bf(acc[m][nb][r]);
        }
    }
  }
}

// ---------------- GroupNorm 2 (192 ch, 16 groups), vectorized ----------------
__global__ __launch_bounds__(256) void k_gnstat2(const unsigned short* __restrict__ X, float* __restrict__ part) {
  __shared__ float s1[256], s2[256];
  int b = blockIdx.x, t = threadIdx.x;   // 1920 blocks: ch = b/10, part p = b%10
  int ch = b / 10, pp = b - ch * 10;
  const unsigned short* base = X + (size_t)ch * 160000 + (size_t)pp * 16000;
  float a = 0.f, q = 0.f;
  for (int i = t; i < 2000; i += 256) {
    uint4 u = *(const uint4*)&base[i * 8];
    sum8(u, a, q);
  }
  s1[t] = a; s2[t] = q;
  __syncthreads();
  for (int s = 128; s > 0; s >>= 1) {
    if (t < s) { s1[t] += s1[t + s]; s2[t] += s2[t + s]; }
    __syncthreads();
  }
  if (t == 0) { part[80000 + ch * 10 + pp] = s1[0]; part[81920 + ch * 10 + pp] = s2[0]; }
}

__global__ __launch_bounds__(256) void k_gnred2(const float* __restrict__ part, float* __restrict__ gmv) {
  __shared__ float s1[256], s2[256];
  int g = blockIdx.x, t = threadIdx.x;   // 16 blocks, 120 partials each
  float a = (t < 120) ? part[80000 + g * 120 + t] : 0.f;
  float q = (t < 120) ? part[81920 + g * 120 + t] : 0.f;
  s1[t] = a; s2[t] = q;
  __syncthreads();
  for (int s = 128; s > 0; s >>= 1) {
    if (t < s) { s1[t] += s1[t + s]; s2[t] += s2[t + s]; }
    __syncthreads();
  }
  if (t == 0) {
    float m = s1[0] / 1920000.0f;
    float v = s2[0] / 1920000.0f - m * m;
    gmv[2 * g] = m; gmv[2 * g + 1] = rsqrtf(v + 1e-5f);
  }
}

__global__ __launch_bounds__(256) void k_gnapply2(const unsigned short* __restrict__ X, const float* __restrict__ gmv,
                                                  const float* __restrict__ g, const float* __restrict__ b,
                                                  float* __restrict__ out) {
  for (unsigned i = blockIdx.x * 256 + threadIdx.x; i < 3840000u; i += gridDim.x * 256) {
    unsigned oc = i / 20000u;         // 20000 uint4 per channel row
    unsigned grp = oc / 12u;
    float mean = gmv[grp * 2], rstd = gmv[grp * 2 + 1];
    float gam = g[oc], bet = b[oc];
    unsigned e = i * 8u;
    uint4 u = *(const uint4*)&X[e];
    unsigned wv[4] = {u.x, u.y, u.z, u.w};
    float o[8];
#pragma unroll
    for (int j = 0; j < 4; ++j) {
      float v0 = __uint_as_float((wv[j] & 0xFFFFu) << 16);
      float v1 = __uint_as_float(wv[j] & 0xFFFF0000u);
      o[2 * j] = fmaxf((v0 - mean) * rstd * gam + bet, 0.f);
      o[2 * j + 1] = fmaxf((v1 - mean) * rstd * gam + bet, 0.f);
    }
    *(float4*)&out[e] = make_float4(o[0], o[1], o[2], o[3]);
    *(float4*)&out[e + 4] = make_float4(o[4], o[5], o[6], o[7]);
  }
}

// ---------------- host ----------------
static inline dim3 gemm_grid(int M, int N) { return dim3((M + 127) / 128, (N + 63) / 64); }

extern "C" void kernel_launch(void* const* d_in, const int* in_sizes, int n_in,
                              void* d_out, int out_size, void* d_ws, size_t ws_size,
                              hipStream_t stream) {
  const float* camera_x = (const float*)d_in[0];
  const int* ids = (const int*)d_in[1];
  const float* mask_tok = (const float*)d_in[4];
  const float* vol_emb = (const float*)d_in[5];
  const float* W_tc = (const float*)d_in[6];
  const float* b_tc = (const float*)d_in[7];
  const float* cams_emb = (const float*)d_in[8];
  const float* lvl_emb = (const float*)d_in[9];
  const float* W_off = (const float*)d_in[10];
  const float* b_off = (const float*)d_in[11];
  const float* W_att = (const float*)d_in[12];
  const float* b_att = (const float*)d_in[13];
  const float* W_val = (const float*)d_in[14];
  const float* b_val = (const float*)d_in[15];
  const float* W_out = (const float*)d_in[16];
  const float* b_out = (const float*)d_in[17];
  const float* ln1_g = (const float*)d_in[18];
  const float* ln1_b = (const float*)d_in[19];
  const float* W_ff1 = (const float*)d_in[20];
  const float* b_ff1 = (const float*)d_in[21];
  const float* W_ff2 = (const float*)d_in[22];
  const float* b_ff2 = (const float*)d_in[23];
  const float* ln2_g = (const float*)d_in[24];
  const float* ln2_b = (const float*)d_in[25];
  const float* deconv_w = (const float*)d_in[26];
  const float* gn1_g = (const float*)d_in[27];
  const float* gn1_b = (const float*)d_in[28];
  const float* conv3_w = (const float*)d_in[29];
  const float* gn2_g = (const float*)d_in[30];
  const float* gn2_b = (const float*)d_in[31];

  char* ws = (char*)d_ws;
  float* q             = (float*)(ws + 0);                      // 20.48 MB
  unsigned short* qb   = (unsigned short*)(ws + 20480000);      // 10.24 MB
  float* proj          = (float*)(ws + 30720000);               // 20.48 MB
  float* oa            = (float*)(ws + 51200000);               // 23.04 MB
  unsigned short* aggb = (unsigned short*)(ws + 74240000);      // 10.24 MB
  unsigned short* ffhb = (unsigned short*)(ws + 84480000);      // 20.48 MB
  float* val           = (float*)(ws + 104960000);              // 1.08 MB
  unsigned short* featb= (unsigned short*)(ws + 106041344);     // 0.54 MB
  unsigned short* x1bf = (unsigned short*)(ws + 30720000);      // 81.92 MB (aliases decoder scratch)
  unsigned short* c3   = (unsigned short*)(ws + 112640000);     // 61.44 MB
  unsigned short* Wt_val = (unsigned short*)(ws + 174080000);   // 393216 B
  unsigned short* Wt_oa  = (unsigned short*)(ws + 174473216);   // 442368 B
  unsigned short* Wt_out = (unsigned short*)(ws + 174915584);   // 393216 B
  unsigned short* Wt_ff1 = (unsigned short*)(ws + 175308800);   // 786432 B
  unsigned short* Wt_ff2 = (unsigned short*)(ws + 176095232);   // 786432 B
  unsigned short* Wt_dc  = (unsigned short*)(ws + 176881664);   // 1048576 B
  unsigned short* wc3    = (unsigned short*)(ws + 177930240);   // 2654208 B
  float* part = (float*)(ws + 180584448);                       // 336 KB
  float* gmv1 = (float*)(ws + 180920320);
  float* gmv2 = (float*)(ws + 180920448);
  float* wtcT = (float*)(ws + 180920576);                       // 786432 B

  float* out_x = (float*)d_out;
  float* out_camx = out_x + 30720000;

  // weight prep
  k_wtct<<<768, 256, 0, stream>>>(W_tc, wtcT);
  k_wt<<<(3 * 65536 + 255) / 256, 256, 0, stream>>>(W_val, Wt_val, 256, 256, 65536, 3 * 65536);
  k_wt<<<(3 * 49152 + 255) / 256, 256, 0, stream>>>(W_off, Wt_oa, 256, 192, 73728, 3 * 49152);
  k_wt<<<(3 * 24576 + 255) / 256, 256, 0, stream>>>(W_att, Wt_oa + 192 * 256, 256, 96, 73728, 3 * 24576);
  k_wt<<<(3 * 65536 + 255) / 256, 256, 0, stream>>>(W_out, Wt_out, 256, 256, 65536, 3 * 65536);
  k_wt<<<(3 * 131072 + 255) / 256, 256, 0, stream>>>(W_ff1, Wt_ff1, 256, 512, 131072, 3 * 131072);
  k_wt<<<(3 * 131072 + 255) / 256, 256, 0, stream>>>(W_ff2, Wt_ff2, 512, 256, 131072, 3 * 131072);
  k_wdc<<<2048, 256, 0, stream>>>(deconv_w, Wt_dc);
  k_wc3<<<5184, 256, 0, stream>>>(conv3_w, wc3);

  k_restore<<<3168, 256, 0, stream>>>(camera_x, ids, mask_tok, out_camx);
  k_vf<<<1056, 256, 0, stream>>>(out_camx, wtcT, b_tc, cams_emb, lvl_emb, featb);
  hipMemcpyAsync(q, vol_emb, (size_t)20000 * 256 * 4, hipMemcpyDeviceToDevice, stream);
  k_cvt<<<20000, 256, 0, stream>>>(vol_emb, qb, 5120000);

  for (int lyr = 0; lyr < 3; ++lyr) {
    k_gemm<<<gemm_grid(1056, 256), 256, 0, stream>>>(featb, 1056, 256, Wt_val + lyr * 65536, 256, 256,
                                                     b_val + lyr * 256, nullptr, 256, 0, val, nullptr, 256, 0);
    k_gemm<<<gemm_grid(20000, 288), 256, 0, stream>>>(qb, 20000, 256, Wt_oa + lyr * 73728, 256, 288,
                                                      b_off + lyr * 192, b_att + lyr * 96, 192, 0,
                                                      oa, nullptr, 288, 0);
    k_sample<<<20000, 256, 0, stream>>>(oa, val, aggb);
    k_gemm<<<gemm_grid(20000, 256), 256, 0, stream>>>(aggb, 20000, 256, Wt_out + lyr * 65536, 256, 256,
                                                      b_out + lyr * 256, nullptr, 256, 0, proj, nullptr, 256, 0);
    k_addln<<<20000, 256, 0, stream>>>(q, proj, ln1_g + lyr * 256, ln1_b + lyr * 256, qb);
    k_gemm<<<gemm_grid(20000, 512), 256, 0, stream>>>(qb, 20000, 256, Wt_ff1 + lyr * 131072, 256, 512,
                                                      b_ff1 + lyr * 512, nullptr, 512, 1, nullptr, ffhb, 512, 2);
    k_gemm<<<gemm_grid(20000, 256), 256, 0, stream>>>(ffhb, 20000, 512, Wt_ff2 + lyr * 131072, 512, 256,
                                                      b_ff2 + lyr * 256, nullptr, 256, 0, proj, nullptr, 256, 0);
    k_addln<<<20000, 256, 0, stream>>>(q, proj, ln2_g + lyr * 256, ln2_b + lyr * 256, qb);
  }

  // deconv: all 8 taps in one GEMM (N = 2048), scattered bf16 output
  k_gemm<<<gemm_grid(20000, 2048), 256, 0, stream>>>(qb, 20000, 256, Wt_dc, 256, 2048,
                                                     nullptr, nullptr, 2048, 0, nullptr, x1bf, 256, 1);

  k_gnstat1<<<2500, 256, 0, stream>>>(x1bf, part);
  k_gnred1<<<16, 256, 0, stream>>>(part, gmv1);
  k_gnapply1<<<2048, 256, 0, stream>>>(x1bf, gmv1, gn1_g, gn1_b);

  k_conv3<<<1300, 256, 0, stream>>>(x1bf, wc3, c3);

  k_gnstat2<<<1920, 256, 0, stream>>>(c3, part);
  k_gnred2<<<16, 256, 0, stream>>>(part, gmv2);
  k_gnapply2<<<2048, 256, 0, stream>>>(c3, gmv2, gn2_g, gn2_b, out_x);
}